// Round 1
// baseline (5757.412 us; speedup 1.0000x reference)
//
#include <hip/hip_runtime.h>

#define F_IN 128
#define F_OUT 64

// ---------------- degree count: deg[col[e]] += 1 ----------------
__global__ void deg_kernel(const int* __restrict__ col, float* __restrict__ deg, int E) {
    int e = blockIdx.x * blockDim.x + threadIdx.x;
    if (e < E) atomicAdd(&deg[col[e]], 1.0f);
}

// ---------------- dinv[v] = rsqrt(deg[v] + 1) (self-loop) ----------------
__global__ void dinv_kernel(float* __restrict__ deg, int N) {
    int v = blockIdx.x * blockDim.x + threadIdx.x;
    if (v < N) deg[v] = rsqrtf(deg[v] + 1.0f);
}

// ---------------- y[v][0:64] = x[v] @ Wmu ; y[v][64:128] = x[v] @ Wls ----------------
// block = 128 threads, each block does 16 nodes. Thread j owns output column j.
// Register-blocking: one W element load feeds 16 FMAs (one per node).
__global__ void gemm_kernel(const float* __restrict__ x, const float* __restrict__ Wmu,
                            const float* __restrict__ Wls, float* __restrict__ y, int N) {
    __shared__ float xs[16 * F_IN];
    const int j = threadIdx.x; // 0..127
    const float* Wcol = (j < F_OUT) ? (Wmu + j) : (Wls + (j - F_OUT));
    const int base = blockIdx.x * 16;
    if (base >= N) return;
    const int nn = min(16, N - base);
    // cooperative coalesced load of the 16-node x tile
    for (int idx = j; idx < nn * F_IN; idx += 128)
        xs[idx] = x[(size_t)base * F_IN + idx];
    __syncthreads();
    float acc[16];
#pragma unroll
    for (int n = 0; n < 16; n++) acc[n] = 0.f;
    for (int k = 0; k < F_IN; k++) {
        const float w = Wcol[(size_t)k * F_OUT];
#pragma unroll
        for (int n = 0; n < 16; n++) acc[n] = fmaf(xs[n * F_IN + k], w, acc[n]);
    }
    for (int n = 0; n < nn; n++)
        y[(size_t)(base + n) * F_IN + j] = acc[n];
}

// ---------------- out = bias + y * dinv^2 (self-loop term), fully writes d_out ----------------
__global__ void init_kernel(const float* __restrict__ y, const float* __restrict__ dinv,
                            const float* __restrict__ bmu, const float* __restrict__ bls,
                            float* __restrict__ out, int N) {
    int t = blockIdx.x * blockDim.x + threadIdx.x;
    if (t >= N * 16) return;
    const int v = t >> 4;     // node
    const int q = t & 15;     // float4 index within 64 floats
    const float d = dinv[v];
    const float s = d * d;
    const float4* y4 = (const float4*)y;
    float4 m = y4[(size_t)v * 32 + q];        // mu part
    float4 l = y4[(size_t)v * 32 + 16 + q];   // logstd part
    float4 bm = ((const float4*)bmu)[q];
    float4 bl = ((const float4*)bls)[q];
    float4 om = make_float4(bm.x + m.x * s, bm.y + m.y * s, bm.z + m.z * s, bm.w + m.w * s);
    float4 ol = make_float4(bl.x + l.x * s, bl.y + l.y * s, bl.z + l.z * s, bl.w + l.w * s);
    ((float4*)out)[(size_t)v * 16 + q] = om;
    ((float4*)out)[(size_t)N * 16 + (size_t)v * 16 + q] = ol;
}

// ---------------- edge scatter: 32 lanes per edge, float4 gather + 4 atomics each ----------------
__global__ void scatter_kernel(const int* __restrict__ row, const int* __restrict__ col,
                               const float* __restrict__ dinv, const float* __restrict__ y,
                               float* __restrict__ out, int E, int N) {
    const long long t = (long long)blockIdx.x * blockDim.x + threadIdx.x;
    const int e = (int)(t >> 5);
    const int l = (int)(t & 31);
    if (e >= E) return;
    const int r = row[e];
    const int c = col[e];
    const float coef = dinv[r] * dinv[c];
    float4 v = ((const float4*)(y + (size_t)r * F_IN))[l];
    float* dst;
    if (l < 16) dst = out + (size_t)c * F_OUT + l * 4;                       // mu
    else        dst = out + (size_t)N * F_OUT + (size_t)c * F_OUT + (l - 16) * 4; // logstd
    atomicAdd(dst + 0, v.x * coef);
    atomicAdd(dst + 1, v.y * coef);
    atomicAdd(dst + 2, v.z * coef);
    atomicAdd(dst + 3, v.w * coef);
}

extern "C" void kernel_launch(void* const* d_in, const int* in_sizes, int n_in,
                              void* d_out, int out_size, void* d_ws, size_t ws_size,
                              hipStream_t stream) {
    const float* x   = (const float*)d_in[0];
    const int*   ei  = (const int*)d_in[1];
    const float* Wmu = (const float*)d_in[2];
    const float* bmu = (const float*)d_in[3];
    const float* Wls = (const float*)d_in[4];
    const float* bls = (const float*)d_in[5];
    float* out = (float*)d_out;

    const int N = in_sizes[0] / F_IN;     // 100000
    const int E = in_sizes[1] / 2;        // 3200000
    const int* row = ei;
    const int* col = ei + E;

    // workspace layout: [deg/dinv: N floats][pad to 512B][y: N*128 floats]
    float* deg = (float*)d_ws;
    size_t deg_bytes = ((size_t)N * sizeof(float) + 511) & ~(size_t)511;
    float* y = (float*)((char*)d_ws + deg_bytes);

    hipMemsetAsync(deg, 0, (size_t)N * sizeof(float), stream);
    deg_kernel<<<(E + 255) / 256, 256, 0, stream>>>(col, deg, E);
    dinv_kernel<<<(N + 255) / 256, 256, 0, stream>>>(deg, N);
    gemm_kernel<<<(N + 15) / 16, 128, 0, stream>>>(x, Wmu, Wls, y, N);
    init_kernel<<<((size_t)N * 16 + 255) / 256, 256, 0, stream>>>(y, deg, bmu, bls, out, N);
    const long long scat_threads = (long long)E * 32;
    scatter_kernel<<<(int)((scat_threads + 255) / 256), 256, 0, stream>>>(row, col, deg, y, out, E, N);
}

// Round 2
// 789.766 us; speedup vs baseline: 7.2900x; 7.2900x over previous
//
#include <hip/hip_runtime.h>

#define F_IN 128
#define F_OUT 64

// ---------------- degree count (int): deg[col[e]] += 1 ----------------
__global__ void deg_kernel(const int* __restrict__ col, int* __restrict__ deg, int E) {
    int e = blockIdx.x * blockDim.x + threadIdx.x;
    if (e < E) atomicAdd(&deg[col[e]], 1);
}

// ---------------- dinv[v] = rsqrt(deg[v] + 1) (self-loop) ----------------
__global__ void dinv_kernel(const int* __restrict__ deg, float* __restrict__ dinv, int N) {
    int v = blockIdx.x * blockDim.x + threadIdx.x;
    if (v < N) dinv[v] = rsqrtf((float)deg[v] + 1.0f);
}

// ---------------- scan level 1: per-block (1024 elems) exclusive scan + block sums ----------------
__global__ void scan1_kernel(const int* __restrict__ deg, int* __restrict__ excl,
                             int* __restrict__ blksum, int N) {
    __shared__ int sdata[256];
    const int t = threadIdx.x;
    const int base = blockIdx.x * 1024 + t * 4;
    int v0 = (base + 0 < N) ? deg[base + 0] : 0;
    int v1 = (base + 1 < N) ? deg[base + 1] : 0;
    int v2 = (base + 2 < N) ? deg[base + 2] : 0;
    int v3 = (base + 3 < N) ? deg[base + 3] : 0;
    const int tot = v0 + v1 + v2 + v3;
    sdata[t] = tot;
    __syncthreads();
    for (int off = 1; off < 256; off <<= 1) {
        int tmp = (t >= off) ? sdata[t - off] : 0;
        __syncthreads();
        sdata[t] += tmp;
        __syncthreads();
    }
    const int exclT = sdata[t] - tot;   // exclusive within block
    if (base + 0 < N) excl[base + 0] = exclT;
    if (base + 1 < N) excl[base + 1] = exclT + v0;
    if (base + 2 < N) excl[base + 2] = exclT + v0 + v1;
    if (base + 3 < N) excl[base + 3] = exclT + v0 + v1 + v2;
    if (t == 255) blksum[blockIdx.x] = sdata[255];
}

// ---------------- scan level 2: exclusive scan of block sums (single block) ----------------
__global__ void scan2_kernel(int* __restrict__ blksum, int nb) {
    __shared__ int sdata[1024];
    const int t = threadIdx.x;
    const int v = (t < nb) ? blksum[t] : 0;
    sdata[t] = v;
    __syncthreads();
    for (int off = 1; off < 1024; off <<= 1) {
        int tmp = (t >= off) ? sdata[t - off] : 0;
        __syncthreads();
        sdata[t] += tmp;
        __syncthreads();
    }
    if (t < nb) blksum[t] = sdata[t] - v;  // exclusive
}

// ---------------- scan level 3: cursor[i] = excl[i] + blksum[i/1024] (in excl array) ----------------
__global__ void scan3_kernel(int* __restrict__ cursor, const int* __restrict__ blksum, int N) {
    int i = blockIdx.x * blockDim.x + threadIdx.x;
    if (i < N) cursor[i] += blksum[i >> 10];
}

// ---------------- CSR fill: counting-sort edges by destination ----------------
__global__ void fill_kernel(const int* __restrict__ row, const int* __restrict__ col,
                            int* __restrict__ cursor, int* __restrict__ srcs, int E) {
    int e = blockIdx.x * blockDim.x + threadIdx.x;
    if (e < E) {
        int pos = atomicAdd(&cursor[col[e]], 1);
        srcs[pos] = row[e];
    }
}

// ---------------- y'[v] = (x[v] @ [Wmu|Wls]) * dinv[v] ----------------
// 128 threads/block, 16 nodes/block; thread j owns output column j; W element reused 16x.
__global__ void gemm_kernel(const float* __restrict__ x, const float* __restrict__ Wmu,
                            const float* __restrict__ Wls, const float* __restrict__ dinv,
                            float* __restrict__ y, int N) {
    __shared__ float xs[16 * F_IN];
    const int j = threadIdx.x; // 0..127
    const float* Wcol = (j < F_OUT) ? (Wmu + j) : (Wls + (j - F_OUT));
    const int base = blockIdx.x * 16;
    if (base >= N) return;
    const int nn = min(16, N - base);
    for (int idx = j; idx < nn * F_IN; idx += 128)
        xs[idx] = x[(size_t)base * F_IN + idx];
    __syncthreads();
    float acc[16];
#pragma unroll
    for (int n = 0; n < 16; n++) acc[n] = 0.f;
    for (int k = 0; k < F_IN; k++) {
        const float w = Wcol[(size_t)k * F_OUT];
#pragma unroll
        for (int n = 0; n < 16; n++) acc[n] = fmaf(xs[n * F_IN + k], w, acc[n]);
    }
    for (int n = 0; n < nn; n++)
        y[(size_t)(base + n) * F_IN + j] = acc[n] * dinv[base + n];
}

// ---------------- gather: one block (128 thr) per node; out = b + dinv[c]*(y'[c] + sum y'[srcs]) ----------------
__global__ void gather_kernel(const int* __restrict__ cursor, const int* __restrict__ deg,
                              const int* __restrict__ srcs, const float* __restrict__ y,
                              const float* __restrict__ dinv, const float* __restrict__ bmu,
                              const float* __restrict__ bls, float* __restrict__ out, int N) {
    const int c = blockIdx.x;
    const int t = threadIdx.x;                 // feature 0..127
    const int end = cursor[c];                 // after fill: row_ptr[c] + deg[c]
    const int start = end - deg[c];
    float a0 = 0.f, a1 = 0.f, a2 = 0.f, a3 = 0.f;
    int i = start;
    for (; i + 4 <= end; i += 4) {
        const int r0 = srcs[i + 0];
        const int r1 = srcs[i + 1];
        const int r2 = srcs[i + 2];
        const int r3 = srcs[i + 3];
        a0 += y[(size_t)r0 * F_IN + t];
        a1 += y[(size_t)r1 * F_IN + t];
        a2 += y[(size_t)r2 * F_IN + t];
        a3 += y[(size_t)r3 * F_IN + t];
    }
    for (; i < end; i++)
        a0 += y[(size_t)srcs[i] * F_IN + t];
    const float acc = (a0 + a1) + (a2 + a3);
    const float self = y[(size_t)c * F_IN + t];
    const float res = dinv[c] * (self + acc);
    if (t < F_OUT)
        out[(size_t)c * F_OUT + t] = bmu[t] + res;
    else
        out[(size_t)N * F_OUT + (size_t)c * F_OUT + (t - F_OUT)] = bls[t - F_OUT] + res;
}

extern "C" void kernel_launch(void* const* d_in, const int* in_sizes, int n_in,
                              void* d_out, int out_size, void* d_ws, size_t ws_size,
                              hipStream_t stream) {
    const float* x   = (const float*)d_in[0];
    const int*   ei  = (const int*)d_in[1];
    const float* Wmu = (const float*)d_in[2];
    const float* bmu = (const float*)d_in[3];
    const float* Wls = (const float*)d_in[4];
    const float* bls = (const float*)d_in[5];
    float* out = (float*)d_out;

    const int N = in_sizes[0] / F_IN;     // 100000
    const int E = in_sizes[1] / 2;        // 3200000
    const int* row = ei;
    const int* col = ei + E;

    // workspace layout (all 512B aligned):
    // [deg: N int][dinv: N f32][cursor: N int][blksum: 1024 int][srcs: E int][y: N*128 f32]
    char* p = (char*)d_ws;
    auto alloc = [&](size_t bytes) {
        char* r = p;
        p += (bytes + 511) & ~(size_t)511;
        return r;
    };
    int*   deg    = (int*)  alloc((size_t)N * 4);
    float* dinv   = (float*)alloc((size_t)N * 4);
    int*   cursor = (int*)  alloc((size_t)N * 4);
    int*   blksum = (int*)  alloc(1024 * 4);
    int*   srcs   = (int*)  alloc((size_t)E * 4);
    float* y      = (float*)alloc((size_t)N * F_IN * 4);

    const int nb1 = (N + 1023) / 1024;    // scan level-1 blocks (98)

    hipMemsetAsync(deg, 0, (size_t)N * sizeof(int), stream);
    deg_kernel<<<(E + 255) / 256, 256, 0, stream>>>(col, deg, E);
    dinv_kernel<<<(N + 255) / 256, 256, 0, stream>>>(deg, dinv, N);
    scan1_kernel<<<nb1, 256, 0, stream>>>(deg, cursor, blksum, N);
    scan2_kernel<<<1, 1024, 0, stream>>>(blksum, nb1);
    scan3_kernel<<<(N + 255) / 256, 256, 0, stream>>>(cursor, blksum, N);
    fill_kernel<<<(E + 255) / 256, 256, 0, stream>>>(row, col, cursor, srcs, E);
    gemm_kernel<<<(N + 15) / 16, 128, 0, stream>>>(x, Wmu, Wls, dinv, y, N);
    gather_kernel<<<N, 128, 0, stream>>>(cursor, deg, srcs, y, dinv, bmu, bls, out, N);
}

// Round 3
// 558.840 us; speedup vs baseline: 10.3024x; 1.4132x over previous
//
#include <hip/hip_runtime.h>

#define F_IN 128
#define F_OUT 64

// ---- bf16 helpers (manual, RTN) ----
__device__ inline float bf2f(unsigned short u) {
    unsigned int v = ((unsigned int)u) << 16;
    return __builtin_bit_cast(float, v);
}
__device__ inline unsigned short f2bf(float f) {
    unsigned int x = __builtin_bit_cast(unsigned int, f);
    unsigned int r = x + 0x7FFFu + ((x >> 16) & 1u);
    return (unsigned short)(r >> 16);
}

// ---------------- A1: coarse bucket histogram (bucket = col >> 7) ----------------
__global__ void bucket_count(const int* __restrict__ col, int* __restrict__ bcount,
                             int E, int NB) {
    __shared__ int h[1024];
    for (int i = threadIdx.x; i < NB; i += 256) h[i] = 0;
    __syncthreads();
    for (int e = blockIdx.x * 256 + threadIdx.x; e < E; e += gridDim.x * 256)
        atomicAdd(&h[col[e] >> 7], 1);
    __syncthreads();
    for (int i = threadIdx.x; i < NB; i += 256) {
        int v = h[i];
        if (v) atomicAdd(&bcount[i], v);
    }
}

// ---------------- A1b: scan bucket counts (single block, NB <= 1024) ----------------
__global__ void bucket_scan(const int* __restrict__ bcount, int* __restrict__ bbase,
                            int* __restrict__ bcursor, int NB) {
    __shared__ int s[1024];
    const int t = threadIdx.x;
    const int v = (t < NB) ? bcount[t] : 0;
    s[t] = v;
    __syncthreads();
    for (int off = 1; off < 1024; off <<= 1) {
        int tmp = (t >= off) ? s[t - off] : 0;
        __syncthreads();
        s[t] += tmp;
        __syncthreads();
    }
    if (t < NB) {
        bbase[t + 1] = s[t];           // inclusive -> base of next
        bcursor[t * 16] = s[t] - v;    // exclusive base, 64B-strided cursors
    }
    if (t == 0) bbase[0] = 0;
}

// ---------------- A2: append edges into buckets, packed (col_local<<17 | row) ----------------
__global__ void bucket_fill(const int* __restrict__ row, const int* __restrict__ col,
                            int* __restrict__ bcursor, int* __restrict__ bpacked, int E) {
    int e = blockIdx.x * blockDim.x + threadIdx.x;
    if (e < E) {
        const int c = col[e];
        const int b = c >> 7;
        const int pos = atomicAdd(&bcursor[b * 16], 1);
        bpacked[pos] = row[e] | ((c & 127) << 17);
    }
}

// ---------------- B1: per-bucket — deg hist, dinv, seg bounds, node-sorted srcs ----------------
__global__ void build_kernel(const int* __restrict__ bbase, const int* __restrict__ bpacked,
                             int* __restrict__ srcs, float* __restrict__ dinv,
                             int2* __restrict__ segs, int N) {
    const int b = blockIdx.x;
    const int lo = bbase[b], hi = bbase[b + 1];
    __shared__ int hist[128];
    __shared__ int excl[128];
    __shared__ int cursor[128];
    const int t = threadIdx.x;   // 256 threads
    if (t < 128) hist[t] = 0;
    __syncthreads();
    for (int i = lo + t; i < hi; i += 256)
        atomicAdd(&hist[bpacked[i] >> 17], 1);
    __syncthreads();
    if (t < 128) excl[t] = hist[t];
    __syncthreads();
    for (int off = 1; off < 128; off <<= 1) {
        int v = (t < 128 && t >= off) ? excl[t - off] : 0;
        __syncthreads();
        if (t < 128) excl[t] += v;
        __syncthreads();
    }
    if (t < 128) {
        const int ex = excl[t] - hist[t];   // exclusive within bucket
        cursor[t] = ex;
        const int node = b * 128 + t;
        if (node < N) {
            dinv[node] = rsqrtf((float)hist[t] + 1.0f);   // +1 self-loop
            segs[node] = make_int2(lo + ex, hist[t]);
        }
    }
    __syncthreads();
    for (int i = lo + t; i < hi; i += 256) {
        const int p = bpacked[i];
        const int pos = atomicAdd(&cursor[p >> 17], 1);
        srcs[lo + pos] = p & 0x1FFFF;
    }
}

// ---------------- y'[v] = (x[v] @ [Wmu|Wls]) * dinv[v], stored bf16 ----------------
__global__ void gemm_kernel(const float* __restrict__ x, const float* __restrict__ Wmu,
                            const float* __restrict__ Wls, const float* __restrict__ dinv,
                            unsigned short* __restrict__ y, int N) {
    __shared__ float xs[16 * F_IN];
    const int j = threadIdx.x; // 0..127
    const float* Wcol = (j < F_OUT) ? (Wmu + j) : (Wls + (j - F_OUT));
    const int base = blockIdx.x * 16;
    if (base >= N) return;
    const int nn = min(16, N - base);
    for (int idx = j; idx < nn * F_IN; idx += 128)
        xs[idx] = x[(size_t)base * F_IN + idx];
    __syncthreads();
    float acc[16];
#pragma unroll
    for (int n = 0; n < 16; n++) acc[n] = 0.f;
    for (int k = 0; k < F_IN; k++) {
        const float w = Wcol[(size_t)k * F_OUT];
#pragma unroll
        for (int n = 0; n < 16; n++) acc[n] = fmaf(xs[n * F_IN + k], w, acc[n]);
    }
    for (int n = 0; n < nn; n++)
        y[(size_t)(base + n) * F_IN + j] = f2bf(acc[n] * dinv[base + n]);
}

// ---------------- gather: one block (128 thr) per node ----------------
__global__ void gather_kernel(const int2* __restrict__ segs, const int* __restrict__ srcs,
                              const unsigned short* __restrict__ y, const float* __restrict__ dinv,
                              const float* __restrict__ bmu, const float* __restrict__ bls,
                              float* __restrict__ out, int N) {
    const int c = blockIdx.x;
    const int t = threadIdx.x;   // feature 0..127
    const int2 sg = segs[c];
    const int start = sg.x;
    const int end = sg.x + sg.y;
    float a0 = 0.f, a1 = 0.f, a2 = 0.f, a3 = 0.f;
    int i = start;
    for (; i + 4 <= end; i += 4) {
        const int r0 = srcs[i + 0];
        const int r1 = srcs[i + 1];
        const int r2 = srcs[i + 2];
        const int r3 = srcs[i + 3];
        a0 += bf2f(y[(size_t)r0 * F_IN + t]);
        a1 += bf2f(y[(size_t)r1 * F_IN + t]);
        a2 += bf2f(y[(size_t)r2 * F_IN + t]);
        a3 += bf2f(y[(size_t)r3 * F_IN + t]);
    }
    for (; i < end; i++)
        a0 += bf2f(y[(size_t)srcs[i] * F_IN + t]);
    const float acc = (a0 + a1) + (a2 + a3);
    const float self = bf2f(y[(size_t)c * F_IN + t]);
    const float res = dinv[c] * (self + acc);
    if (t < F_OUT)
        out[(size_t)c * F_OUT + t] = bmu[t] + res;
    else
        out[(size_t)N * F_OUT + (size_t)c * F_OUT + (t - F_OUT)] = bls[t - F_OUT] + res;
}

extern "C" void kernel_launch(void* const* d_in, const int* in_sizes, int n_in,
                              void* d_out, int out_size, void* d_ws, size_t ws_size,
                              hipStream_t stream) {
    const float* x   = (const float*)d_in[0];
    const int*   ei  = (const int*)d_in[1];
    const float* Wmu = (const float*)d_in[2];
    const float* bmu = (const float*)d_in[3];
    const float* Wls = (const float*)d_in[4];
    const float* bls = (const float*)d_in[5];
    float* out = (float*)d_out;

    const int N = in_sizes[0] / F_IN;     // 100000
    const int E = in_sizes[1] / 2;        // 3200000
    const int* row = ei;
    const int* col = ei + E;
    const int NB = (N + 127) >> 7;        // 782 buckets of 128 nodes

    // workspace layout (512B aligned):
    char* p = (char*)d_ws;
    auto alloc = [&](size_t bytes) {
        char* r = p;
        p += (bytes + 511) & ~(size_t)511;
        return r;
    };
    int*   bcount  = (int*)  alloc((size_t)NB * 4);
    int*   bbase   = (int*)  alloc((size_t)(NB + 1) * 4);
    int*   bcursor = (int*)  alloc((size_t)NB * 16 * 4);   // 64B-strided cursors
    int*   bpacked = (int*)  alloc((size_t)E * 4);
    int*   srcs    = (int*)  alloc((size_t)E * 4);
    int2*  segs    = (int2*) alloc((size_t)N * 8);
    float* dinv    = (float*)alloc((size_t)N * 4);
    unsigned short* y = (unsigned short*)alloc((size_t)N * F_IN * 2);

    hipMemsetAsync(bcount, 0, (size_t)NB * 4, stream);
    bucket_count<<<256, 256, 0, stream>>>(col, bcount, E, NB);
    bucket_scan<<<1, 1024, 0, stream>>>(bcount, bbase, bcursor, NB);
    bucket_fill<<<(E + 255) / 256, 256, 0, stream>>>(row, col, bcursor, bpacked, E);
    build_kernel<<<NB, 256, 0, stream>>>(bbase, bpacked, srcs, dinv, segs, N);
    gemm_kernel<<<(N + 15) / 16, 128, 0, stream>>>(x, Wmu, Wls, dinv, y, N);
    gather_kernel<<<N, 128, 0, stream>>>(segs, srcs, y, dinv, bmu, bls, out, N);
}

// Round 4
// 452.105 us; speedup vs baseline: 12.7347x; 1.2361x over previous
//
#include <hip/hip_runtime.h>

#define F_IN 128
#define F_OUT 64
#define TILE 8192

// ---- bf16 helpers (manual, RTN) ----
__device__ inline float bf2f(unsigned short u) {
    unsigned int v = ((unsigned int)u) << 16;
    return __builtin_bit_cast(float, v);
}
__device__ inline unsigned short f2bf(float f) {
    unsigned int x = __builtin_bit_cast(unsigned int, f);
    unsigned int r = x + 0x7FFFu + ((x >> 16) & 1u);
    return (unsigned short)(r >> 16);
}

// ---------------- A1: coarse bucket histogram (bucket = col >> 7) ----------------
__global__ void bucket_count(const int* __restrict__ col, int* __restrict__ bcount,
                             int E, int NB) {
    __shared__ int h[1024];
    for (int i = threadIdx.x; i < NB; i += 256) h[i] = 0;
    __syncthreads();
    for (int e = blockIdx.x * 256 + threadIdx.x; e < E; e += gridDim.x * 256)
        atomicAdd(&h[col[e] >> 7], 1);
    __syncthreads();
    for (int i = threadIdx.x; i < NB; i += 256) {
        int v = h[i];
        if (v) atomicAdd(&bcount[i], v);
    }
}

// ---------------- A1b: scan bucket counts (single block, NB <= 1024) ----------------
__global__ void bucket_scan(const int* __restrict__ bcount, int* __restrict__ bbase,
                            int* __restrict__ bcursor, int NB) {
    __shared__ int s[1024];
    const int t = threadIdx.x;
    const int v = (t < NB) ? bcount[t] : 0;
    s[t] = v;
    __syncthreads();
    for (int off = 1; off < 1024; off <<= 1) {
        int tmp = (t >= off) ? s[t - off] : 0;
        __syncthreads();
        s[t] += tmp;
        __syncthreads();
    }
    if (t < NB) {
        bbase[t + 1] = s[t];           // inclusive -> base of next
        bcursor[t * 16] = s[t] - v;    // exclusive base, 64B-strided cursors
    }
    if (t == 0) bbase[0] = 0;
}

// ---------------- A2: tile-privatized fill — each tile reserves private sub-ranges ----------------
// Phase 1: LDS hist of this tile's 8192 edges. Phase 2: one global atomic per bucket
// reserves a PRIVATE contiguous range (no cross-workgroup line sharing except range
// boundaries -> write amplification <= 2x). Phase 3: scatter into private ranges.
__global__ void tile_fill(const int* __restrict__ row, const int* __restrict__ col,
                          int* __restrict__ gcursor, int* __restrict__ bpacked,
                          int E, int NB) {
    __shared__ int hist[1024];
    __shared__ int cur[1024];
    const int base = blockIdx.x * TILE;
    const int n = min(TILE, E - base);
    for (int i = threadIdx.x; i < NB; i += 256) hist[i] = 0;
    __syncthreads();
    for (int i = threadIdx.x; i < n; i += 256)
        atomicAdd(&hist[col[base + i] >> 7], 1);
    __syncthreads();
    for (int b = threadIdx.x; b < NB; b += 256) {
        const int h = hist[b];
        cur[b] = h ? atomicAdd(&gcursor[b * 16], h) : 0;
    }
    __syncthreads();
    for (int i = threadIdx.x; i < n; i += 256) {
        const int c = col[base + i];
        const int b = c >> 7;
        const int pos = atomicAdd(&cur[b], 1);
        bpacked[pos] = row[base + i] | ((c & 127) << 17);
    }
}

// ---------------- B1: per-bucket — deg hist, dinv, seg bounds, node-sorted srcs ----------------
__global__ void build_kernel(const int* __restrict__ bbase, const int* __restrict__ bpacked,
                             int* __restrict__ srcs, float* __restrict__ dinv,
                             int2* __restrict__ segs, int N) {
    const int b = blockIdx.x;
    const int lo = bbase[b], hi = bbase[b + 1];
    __shared__ int hist[128];
    __shared__ int excl[128];
    __shared__ int cursor[128];
    const int t = threadIdx.x;   // 256 threads
    if (t < 128) hist[t] = 0;
    __syncthreads();
    for (int i = lo + t; i < hi; i += 256)
        atomicAdd(&hist[bpacked[i] >> 17], 1);
    __syncthreads();
    if (t < 128) excl[t] = hist[t];
    __syncthreads();
    for (int off = 1; off < 128; off <<= 1) {
        int v = (t < 128 && t >= off) ? excl[t - off] : 0;
        __syncthreads();
        if (t < 128) excl[t] += v;
        __syncthreads();
    }
    if (t < 128) {
        const int ex = excl[t] - hist[t];   // exclusive within bucket
        cursor[t] = ex;
        const int node = b * 128 + t;
        if (node < N) {
            dinv[node] = rsqrtf((float)hist[t] + 1.0f);   // +1 self-loop
            segs[node] = make_int2(lo + ex, hist[t]);
        }
    }
    __syncthreads();
    for (int i = lo + t; i < hi; i += 256) {
        const int p = bpacked[i];
        const int pos = atomicAdd(&cursor[p >> 17], 1);
        srcs[lo + pos] = p & 0x1FFFF;
    }
}

// ---------------- y'[v] = (x[v] @ [Wmu|Wls]) * dinv[v], stored bf16 ----------------
__global__ void gemm_kernel(const float* __restrict__ x, const float* __restrict__ Wmu,
                            const float* __restrict__ Wls, const float* __restrict__ dinv,
                            unsigned short* __restrict__ y, int N) {
    __shared__ float xs[16 * F_IN];
    const int j = threadIdx.x; // 0..127
    const float* Wcol = (j < F_OUT) ? (Wmu + j) : (Wls + (j - F_OUT));
    const int base = blockIdx.x * 16;
    if (base >= N) return;
    const int nn = min(16, N - base);
    for (int idx = j; idx < nn * F_IN; idx += 128)
        xs[idx] = x[(size_t)base * F_IN + idx];
    __syncthreads();
    float acc[16];
#pragma unroll
    for (int n = 0; n < 16; n++) acc[n] = 0.f;
    for (int k = 0; k < F_IN; k++) {
        const float w = Wcol[(size_t)k * F_OUT];
#pragma unroll
        for (int n = 0; n < 16; n++) acc[n] = fmaf(xs[n * F_IN + k], w, acc[n]);
    }
    for (int n = 0; n < nn; n++)
        y[(size_t)(base + n) * F_IN + j] = f2bf(acc[n] * dinv[base + n]);
}

// ---------------- gather: one WAVE per node; lane owns 2 packed-bf16 features ----------------
__global__ void gather_kernel(const int2* __restrict__ segs, const int* __restrict__ srcs,
                              const unsigned int* __restrict__ y2, const float* __restrict__ dinv,
                              const float* __restrict__ bmu, const float* __restrict__ bls,
                              float* __restrict__ out, int N) {
    const int wid = threadIdx.x >> 6;
    const int lane = threadIdx.x & 63;
    const int c = blockIdx.x * 4 + wid;
    if (c >= N) return;
    const int2 sg = segs[c];
    const int start = sg.x, end = sg.x + sg.y;
    float a0 = 0.f, a1 = 0.f, b0 = 0.f, b1 = 0.f;
    float c0 = 0.f, c1 = 0.f, d0 = 0.f, d1 = 0.f;
    int i = start;
    for (; i + 4 <= end; i += 4) {
        const int r0 = srcs[i + 0];
        const int r1 = srcs[i + 1];
        const int r2 = srcs[i + 2];
        const int r3 = srcs[i + 3];
        const unsigned u0 = y2[(size_t)r0 * 64 + lane];
        const unsigned u1 = y2[(size_t)r1 * 64 + lane];
        const unsigned u2 = y2[(size_t)r2 * 64 + lane];
        const unsigned u3 = y2[(size_t)r3 * 64 + lane];
        a0 += bf2f((unsigned short)u0); a1 += bf2f((unsigned short)(u0 >> 16));
        b0 += bf2f((unsigned short)u1); b1 += bf2f((unsigned short)(u1 >> 16));
        c0 += bf2f((unsigned short)u2); c1 += bf2f((unsigned short)(u2 >> 16));
        d0 += bf2f((unsigned short)u3); d1 += bf2f((unsigned short)(u3 >> 16));
    }
    for (; i < end; i++) {
        const unsigned u = y2[(size_t)srcs[i] * 64 + lane];
        a0 += bf2f((unsigned short)u); a1 += bf2f((unsigned short)(u >> 16));
    }
    const unsigned us = y2[(size_t)c * 64 + lane];   // self-loop
    float s0 = (a0 + b0) + (c0 + d0) + bf2f((unsigned short)us);
    float s1 = (a1 + b1) + (c1 + d1) + bf2f((unsigned short)(us >> 16));
    const float dv = dinv[c];
    s0 *= dv;
    s1 *= dv;
    const int f = lane * 2;
    if (f < F_OUT) {
        float2 r = make_float2(bmu[f] + s0, bmu[f + 1] + s1);
        *(float2*)&out[(size_t)c * F_OUT + f] = r;
    } else {
        const int g = f - F_OUT;
        float2 r = make_float2(bls[g] + s0, bls[g + 1] + s1);
        *(float2*)&out[(size_t)N * F_OUT + (size_t)c * F_OUT + g] = r;
    }
}

extern "C" void kernel_launch(void* const* d_in, const int* in_sizes, int n_in,
                              void* d_out, int out_size, void* d_ws, size_t ws_size,
                              hipStream_t stream) {
    const float* x   = (const float*)d_in[0];
    const int*   ei  = (const int*)d_in[1];
    const float* Wmu = (const float*)d_in[2];
    const float* bmu = (const float*)d_in[3];
    const float* Wls = (const float*)d_in[4];
    const float* bls = (const float*)d_in[5];
    float* out = (float*)d_out;

    const int N = in_sizes[0] / F_IN;     // 100000
    const int E = in_sizes[1] / 2;        // 3200000
    const int* row = ei;
    const int* col = ei + E;
    const int NB = (N + 127) >> 7;        // 782 buckets of 128 nodes

    // workspace layout (512B aligned):
    char* p = (char*)d_ws;
    auto alloc = [&](size_t bytes) {
        char* r = p;
        p += (bytes + 511) & ~(size_t)511;
        return r;
    };
    int*   bcount  = (int*)  alloc((size_t)NB * 4);
    int*   bbase   = (int*)  alloc((size_t)(NB + 1) * 4);
    int*   bcursor = (int*)  alloc((size_t)NB * 16 * 4);   // 64B-strided cursors
    int*   bpacked = (int*)  alloc((size_t)E * 4);
    int*   srcs    = (int*)  alloc((size_t)E * 4);
    int2*  segs    = (int2*) alloc((size_t)N * 8);
    float* dinv    = (float*)alloc((size_t)N * 4);
    unsigned short* y = (unsigned short*)alloc((size_t)N * F_IN * 2);

    const int ntiles = (E + TILE - 1) / TILE;

    hipMemsetAsync(bcount, 0, (size_t)NB * 4, stream);
    bucket_count<<<512, 256, 0, stream>>>(col, bcount, E, NB);
    bucket_scan<<<1, 1024, 0, stream>>>(bcount, bbase, bcursor, NB);
    tile_fill<<<ntiles, 256, 0, stream>>>(row, col, bcursor, bpacked, E, NB);
    build_kernel<<<NB, 256, 0, stream>>>(bbase, bpacked, srcs, dinv, segs, N);
    gemm_kernel<<<(N + 15) / 16, 128, 0, stream>>>(x, Wmu, Wls, dinv, y, N);
    gather_kernel<<<(N + 3) / 4, 256, 0, stream>>>(segs, srcs, (const unsigned int*)y,
                                                   dinv, bmu, bls, out, N);
}